// Round 5
// baseline (424.159 us; speedup 1.0000x reference)
//
#include <hip/hip_runtime.h>
#include <stdint.h>

#define NREL 5
#define D 64
#define REC_BYTES 384   // int8 q[5][64] (320) + fp32 scale[5] (20) + fp32 c[5] (20) + pad
#define TI 64           // items per block in item_transform

// round-to-nearest-even fp32 -> bf16 (as uint16)
static __device__ __forceinline__ uint16_t f2bf(float f) {
    uint32_t u = __float_as_uint(f);
    u += 0x7FFFu + ((u >> 16) & 1u);
    return (uint16_t)(u >> 16);
}

#if defined(__has_builtin)
#if __has_builtin(__builtin_amdgcn_sdot4)
#define HAVE_SDOT4 1
#endif
#endif
#ifdef HAVE_SDOT4
static __device__ __forceinline__ int SDOT4(uint32_t a, uint32_t b, int c) {
    return __builtin_amdgcn_sdot4((int)a, (int)b, c, false);
}
#else
static __device__ __forceinline__ int SDOT4(uint32_t a, uint32_t b, int c) {
    c += ((int)(a << 24) >> 24) * ((int)(b << 24) >> 24);
    c += ((int)(a << 16) >> 24) * ((int)(b << 16) >> 24);
    c += ((int)(a << 8) >> 24) * ((int)(b << 8) >> 24);
    c += ((int)a >> 24) * ((int)b >> 24);
    return c;
}
#endif

// Kernel 0: quantize u_features rows to int8 with per-row scale (64B/row).
__global__ __launch_bounds__(256) void u_quant_kernel(
    const float* __restrict__ uf,
    uint32_t* __restrict__ uq,
    float* __restrict__ uscale,
    int nRows)
{
    const int gid = blockIdx.x * 256 + threadIdx.x;
    const int row = gid >> 4;
    const int t = gid & 15;
    if (row >= nRows) return;
    const float4 v = *(const float4*)(uf + (size_t)row * D + t * 4);
    float m = fmaxf(fmaxf(fabsf(v.x), fabsf(v.y)), fmaxf(fabsf(v.z), fabsf(v.w)));
    m = fmaxf(m, __shfl_xor(m, 1));
    m = fmaxf(m, __shfl_xor(m, 2));
    m = fmaxf(m, __shfl_xor(m, 4));
    m = fmaxf(m, __shfl_xor(m, 8));
    m = fmaxf(m, 1e-20f);
    const float qs = 127.0f / m;
    const int q0 = (int)rintf(v.x * qs);
    const int q1 = (int)rintf(v.y * qs);
    const int q2 = (int)rintf(v.z * qs);
    const int q3 = (int)rintf(v.w * qs);
    uq[(size_t)row * (D / 4) + t] = ((uint32_t)(uint8_t)(int8_t)q0)
                                  | ((uint32_t)(uint8_t)(int8_t)q1 << 8)
                                  | ((uint32_t)(uint8_t)(int8_t)q2 << 16)
                                  | ((uint32_t)(uint8_t)(int8_t)q3 << 24);
    if (t == 0) uscale[row] = m * (1.0f / 127.0f);
}

// Kernel 1: per-item transform + int8 quantization. LDS-staged:
//   Wl: W as bf16, layout [r][d4][k][dj] so lane k's 4-d fragment is one b64
//   Il: 64-item fp32 tile, rows contiguous (uniform b128 broadcast reads)
// Wave w computes items w*16..w*16+15; lane owns output column k=lane.
__global__ __launch_bounds__(256) void item_transform_kernel(
    const float* __restrict__ i_feat,
    const float* __restrict__ W,
    const float* __restrict__ b,
    char* __restrict__ recs,
    int nItems)
{
    __shared__ uint16_t Wl[NREL * 16 * D * 4];  // 40 KB
    __shared__ float    Il[TI * D];             // 16 KB

    const int tid = threadIdx.x;
    const int lane = tid & 63;
    const int wv = tid >> 6;
    const int item0 = blockIdx.x * TI;

    // stage W (5120 float4 across 256 threads = 20 iters), fp32 -> bf16
#pragma unroll
    for (int itw = 0; itw < 20; ++itw) {
        const int f4 = itw * 256 + tid;
        const int f = f4 * 4;               // dword index, k-part multiple of 4
        const int r = f >> 12;
        const int d = (f >> 6) & 63;
        const int k = f & 63;
        const float4 v = *(const float4*)(W + f);
        const int base = ((r * 16 + (d >> 2)) * D + k) * 4 + (d & 3);
        Wl[base + 0 * 4] = f2bf(v.x);
        Wl[base + 1 * 4] = f2bf(v.y);
        Wl[base + 2 * 4] = f2bf(v.z);
        Wl[base + 3 * 4] = f2bf(v.w);
    }
    // stage i-tile (1024 float4 = 4 iters), clamp OOB rows
#pragma unroll
    for (int itw = 0; itw < 4; ++itw) {
        const int f4 = itw * 256 + tid;
        const int it = f4 >> 4;
        const int q = f4 & 15;
        int row = item0 + it;
        if (row >= nItems) row = nItems - 1;
        *(float4*)(Il + it * D + q * 4) = *(const float4*)(i_feat + (size_t)row * D + q * 4);
    }
    __syncthreads();

    const int it0 = wv * 16;
    float acc[16][NREL];
#pragma unroll
    for (int it = 0; it < 16; ++it)
#pragma unroll
        for (int r = 0; r < NREL; ++r) acc[it][r] = 0.f;

#pragma unroll 4
    for (int d4 = 0; d4 < 16; ++d4) {
        float wf[NREL][4];
#pragma unroll
        for (int r = 0; r < NREL; ++r) {
            const uint2 w2 = *(const uint2*)&Wl[((r * 16 + d4) * D + lane) * 4];
            wf[r][0] = __uint_as_float(w2.x << 16);
            wf[r][1] = __uint_as_float(w2.x & 0xffff0000u);
            wf[r][2] = __uint_as_float(w2.y << 16);
            wf[r][3] = __uint_as_float(w2.y & 0xffff0000u);
        }
#pragma unroll
        for (int it = 0; it < 16; ++it) {
            const float4 iv = *(const float4*)(Il + (it0 + it) * D + d4 * 4); // uniform bcast
#pragma unroll
            for (int r = 0; r < NREL; ++r) {
                acc[it][r] = fmaf(iv.x, wf[r][0], acc[it][r]);
                acc[it][r] = fmaf(iv.y, wf[r][1], acc[it][r]);
                acc[it][r] = fmaf(iv.z, wf[r][2], acc[it][r]);
                acc[it][r] = fmaf(iv.w, wf[r][3], acc[it][r]);
            }
        }
    }

    // epilogue: per (it,r): wave-max -> int8 -> byte store; bias dot
    float breg[NREL];
#pragma unroll
    for (int r = 0; r < NREL; ++r) breg[r] = b[r * D + lane];

#pragma unroll
    for (int it = 0; it < 16; ++it) {
        if (item0 + it0 + it >= nItems) continue;
        char* rec = recs + (size_t)(item0 + it0 + it) * REC_BYTES;
        const float ii = Il[(it0 + it) * D + lane];
#pragma unroll
        for (int r = 0; r < NREL; ++r) {
            float m = fabsf(acc[it][r]);
            m = fmaxf(m, __shfl_xor(m, 1));
            m = fmaxf(m, __shfl_xor(m, 2));
            m = fmaxf(m, __shfl_xor(m, 4));
            m = fmaxf(m, __shfl_xor(m, 8));
            m = fmaxf(m, __shfl_xor(m, 16));
            m = fmaxf(m, __shfl_xor(m, 32));
            m = fmaxf(m, 1e-20f);
            const float qs = 127.0f / m;
            const int q = (int)rintf(acc[it][r] * qs);
            rec[r * D + lane] = (char)q;
            if (lane == 0) *(float*)(rec + NREL * D + r * 4) = m * (1.0f / 127.0f);

            float p = ii * breg[r];
            p += __shfl_xor(p, 1);
            p += __shfl_xor(p, 2);
            p += __shfl_xor(p, 4);
            p += __shfl_xor(p, 8);
            p += __shfl_xor(p, 16);
            p += __shfl_xor(p, 32);
            if (lane == 0) *(float*)(rec + NREL * D + NREL * 4 + r * 4) = p;
        }
    }
}

// Kernel 2: per-edge gather + int8 dot via sdot4. 4 lanes per edge
// (16 edges/wave, single pass). Lane c of an edge owns bytes c*16..c*16+15.
__global__ __launch_bounds__(256) void edge_kernel(
    const uint32_t* __restrict__ u_q,
    const float* __restrict__ u_scale,
    const int* __restrict__ edge_user,
    const int* __restrict__ edge_item,
    const char* __restrict__ recs,
    float* __restrict__ out,
    int nE)
{
    const int lane = threadIdx.x & 63;
    const int wave = (blockIdx.x * 256 + threadIdx.x) >> 6;
    const int es = lane >> 2;    // edge slot 0..15
    const int c = lane & 3;      // 16B chunk

    const long e = (long)wave * 16 + es;
    if (e >= nE) return;

    const int iu = edge_user[e];
    const int ii = edge_item[e];
    const uint4 uv = *(const uint4*)(u_q + (size_t)iu * (D / 4) + c * 4);
    const char* rec = recs + (size_t)ii * REC_BYTES;

    int s[NREL];
#pragma unroll
    for (int r = 0; r < NREL; ++r) {
        const uint4 yv = *(const uint4*)(rec + r * D + c * 16);
        int t = SDOT4(uv.x, yv.x, 0);
        t = SDOT4(uv.y, yv.y, t);
        t = SDOT4(uv.z, yv.z, t);
        s[r] = SDOT4(uv.w, yv.w, t);
    }
#pragma unroll
    for (int r = 0; r < NREL; ++r) {
        s[r] += __shfl_xor(s[r], 1);
        s[r] += __shfl_xor(s[r], 2);
    }
    const float us = u_scale[iu];
    // lane c writes relation r=c; lane c==0 also writes r=4
    {
        const float ys = *(const float*)(rec + NREL * D + c * 4);
        const float cc = *(const float*)(rec + NREL * D + NREL * 4 + c * 4);
        out[e * NREL + c] = fmaf((float)s[c], us * ys, cc);
    }
    if (c == 0) {
        const float ys = *(const float*)(rec + NREL * D + 4 * 4);
        const float cc = *(const float*)(rec + NREL * D + NREL * 4 + 4 * 4);
        out[e * NREL + 4] = fmaf((float)s[4], us * ys, cc);
    }
}

extern "C" void kernel_launch(void* const* d_in, const int* in_sizes, int n_in,
                              void* d_out, int out_size, void* d_ws, size_t ws_size,
                              hipStream_t stream) {
    const float* u_feat    = (const float*)d_in[0];
    const float* i_feat    = (const float*)d_in[1];
    const int*   edge_user = (const int*)d_in[2];
    const int*   edge_item = (const int*)d_in[3];
    const float* W         = (const float*)d_in[4];
    const float* b         = (const float*)d_in[5];
    float* out = (float*)d_out;

    const int nUsers = in_sizes[0] / D;
    const int nItems = in_sizes[1] / D;
    const int nE = in_sizes[2];

    // workspace: item records | u_q int8 | u_scale fp32
    char* recs = (char*)d_ws;
    size_t off = ((size_t)nItems * REC_BYTES + 255) & ~(size_t)255;
    uint32_t* u_q = (uint32_t*)((char*)d_ws + off);
    off += ((size_t)nUsers * D + 255) & ~(size_t)255;
    float* u_scale = (float*)((char*)d_ws + off);

    {
        const int threads = nUsers * 16;
        u_quant_kernel<<<(threads + 255) / 256, 256, 0, stream>>>(u_feat, u_q, u_scale, nUsers);
    }
    {
        const int blocks = (nItems + TI - 1) / TI;
        item_transform_kernel<<<blocks, 256, 0, stream>>>(i_feat, W, b, recs, nItems);
    }
    {
        const long waves = ((long)nE + 15) / 16;
        const long blocks = (waves + 3) / 4;
        edge_kernel<<<(int)blocks, 256, 0, stream>>>(u_q, u_scale, edge_user, edge_item,
                                                     recs, out, nE);
    }
}

// Round 6
// 411.404 us; speedup vs baseline: 1.0310x; 1.0310x over previous
//
#include <hip/hip_runtime.h>
#include <stdint.h>

#define NREL 5
#define D 64
#define Q_BYTES 320     // int8 q[5][64], exactly 5 cache lines
// sc[item][16] floats (64B): [0..4]=y scale, [5..9]=c bias-dot, rest pad

#if defined(__has_builtin)
#if __has_builtin(__builtin_amdgcn_sdot4)
#define HAVE_SDOT4 1
#endif
#endif
#ifdef HAVE_SDOT4
static __device__ __forceinline__ int SDOT4(uint32_t a, uint32_t b, int c) {
    return __builtin_amdgcn_sdot4((int)a, (int)b, c, false);
}
#else
static __device__ __forceinline__ int SDOT4(uint32_t a, uint32_t b, int c) {
    c += ((int)(a << 24) >> 24) * ((int)(b << 24) >> 24);
    c += ((int)(a << 16) >> 24) * ((int)(b << 16) >> 24);
    c += ((int)(a << 8) >> 24) * ((int)(b << 8) >> 24);
    c += ((int)a >> 24) * ((int)b >> 24);
    return c;
}
#endif

// wave-wide broadcast of lane d's value, immediate lane index, pure VALU
static __device__ __forceinline__ float bcast(float v, int d) {
    return __int_as_float(__builtin_amdgcn_readlane(__float_as_int(v), d));
}

// Kernel 0: quantize u_features rows to int8 with per-row scale (64B/row).
__global__ __launch_bounds__(256) void u_quant_kernel(
    const float* __restrict__ uf,
    uint32_t* __restrict__ uq,
    float* __restrict__ uscale,
    int nRows)
{
    const int gid = blockIdx.x * 256 + threadIdx.x;
    const int row = gid >> 4;
    const int t = gid & 15;
    if (row >= nRows) return;
    const float4 v = *(const float4*)(uf + (size_t)row * D + t * 4);
    float m = fmaxf(fmaxf(fabsf(v.x), fabsf(v.y)), fmaxf(fabsf(v.z), fabsf(v.w)));
    m = fmaxf(m, __shfl_xor(m, 1));
    m = fmaxf(m, __shfl_xor(m, 2));
    m = fmaxf(m, __shfl_xor(m, 4));
    m = fmaxf(m, __shfl_xor(m, 8));
    m = fmaxf(m, 1e-20f);
    const float qs = 127.0f / m;
    const int q0 = (int)rintf(v.x * qs);
    const int q1 = (int)rintf(v.y * qs);
    const int q2 = (int)rintf(v.z * qs);
    const int q3 = (int)rintf(v.w * qs);
    uq[(size_t)row * (D / 4) + t] = ((uint32_t)(uint8_t)(int8_t)q0)
                                  | ((uint32_t)(uint8_t)(int8_t)q1 << 8)
                                  | ((uint32_t)(uint8_t)(int8_t)q2 << 16)
                                  | ((uint32_t)(uint8_t)(int8_t)q3 << 24);
    if (t == 0) uscale[row] = m * (1.0f / 127.0f);
}

// Kernel 1: per-item transform + int8 quantization.
// One wave per (relation, 16 items). Lane owns output column k = lane.
//   acc[it] = sum_d i[item0+it][d] * W[r][d][lane]
// The i-broadcast uses v_readlane (immediate lane index): no LDS, no
// bpermute, no uniform-load gamble. W loads are coalesced dwords and W is
// L1-resident (80 KB total). 15625 waves -> deep TLP, ~50 VGPRs.
__global__ __launch_bounds__(256) void item_transform_kernel(
    const float* __restrict__ i_feat,
    const float* __restrict__ W,
    const float* __restrict__ b,
    char* __restrict__ qrecs,
    float* __restrict__ sc,
    int nItems)
{
    const int lane = threadIdx.x & 63;
    const int wave = (blockIdx.x * 256 + threadIdx.x) >> 6;
    const int nGroups = (nItems + 15) / 16;
    if (wave >= NREL * nGroups) return;
    const int r = wave % NREL;
    const int item0 = (wave / NREL) * 16;

    // lane holds i[item0+it][lane]
    float iv[16];
#pragma unroll
    for (int it = 0; it < 16; ++it) {
        int row = item0 + it;
        if (row >= nItems) row = nItems - 1;
        iv[it] = i_feat[(size_t)row * D + lane];
    }
    const float* Wp = W + r * (D * D);
    const float breg = b[r * D + lane];

    float acc[16];
#pragma unroll
    for (int it = 0; it < 16; ++it) acc[it] = 0.f;

#pragma unroll
    for (int d = 0; d < D; ++d) {
        const float wv = Wp[d * D + lane];
#pragma unroll
        for (int it = 0; it < 16; ++it)
            acc[it] = fmaf(bcast(iv[it], d), wv, acc[it]);
    }

    // epilogue: per item: wave-max -> int8 quantize -> 1B store; bias dot
#pragma unroll
    for (int it = 0; it < 16; ++it) {
        const int row = item0 + it;
        if (row >= nItems) continue;
        float m = fabsf(acc[it]);
        m = fmaxf(m, __shfl_xor(m, 1));
        m = fmaxf(m, __shfl_xor(m, 2));
        m = fmaxf(m, __shfl_xor(m, 4));
        m = fmaxf(m, __shfl_xor(m, 8));
        m = fmaxf(m, __shfl_xor(m, 16));
        m = fmaxf(m, __shfl_xor(m, 32));
        m = fmaxf(m, 1e-20f);
        const float qs = 127.0f / m;
        const int q = (int)rintf(acc[it] * qs);
        qrecs[(size_t)row * Q_BYTES + r * D + lane] = (char)q;

        float p = iv[it] * breg;
        p += __shfl_xor(p, 1);
        p += __shfl_xor(p, 2);
        p += __shfl_xor(p, 4);
        p += __shfl_xor(p, 8);
        p += __shfl_xor(p, 16);
        p += __shfl_xor(p, 32);
        if (lane == 0) {
            sc[(size_t)row * 16 + r] = m * (1.0f / 127.0f);
            sc[(size_t)row * 16 + NREL + r] = p;
        }
    }
}

// Kernel 2: per-edge gather + int8 dot via sdot4. 4 lanes per edge
// (16 edges/wave). Lane c owns bytes c*16..c*16+15 of each q-row.
__global__ __launch_bounds__(256) void edge_kernel(
    const uint32_t* __restrict__ u_q,
    const float* __restrict__ u_scale,
    const int* __restrict__ edge_user,
    const int* __restrict__ edge_item,
    const char* __restrict__ qrecs,
    const float* __restrict__ sc,
    float* __restrict__ out,
    int nE)
{
    const int lane = threadIdx.x & 63;
    const int wave = (blockIdx.x * 256 + threadIdx.x) >> 6;
    const int es = lane >> 2;    // edge slot 0..15
    const int c = lane & 3;      // 16B chunk

    const long e = (long)wave * 16 + es;
    if (e >= nE) return;

    const int iu = edge_user[e];
    const int ii = edge_item[e];
    const uint4 uv = *(const uint4*)(u_q + (size_t)iu * (D / 4) + c * 4);
    const char* rec = qrecs + (size_t)ii * Q_BYTES;

    int s[NREL];
#pragma unroll
    for (int r = 0; r < NREL; ++r) {
        const uint4 yv = *(const uint4*)(rec + r * D + c * 16);
        int t = SDOT4(uv.x, yv.x, 0);
        t = SDOT4(uv.y, yv.y, t);
        t = SDOT4(uv.z, yv.z, t);
        s[r] = SDOT4(uv.w, yv.w, t);
    }
#pragma unroll
    for (int r = 0; r < NREL; ++r) {
        s[r] += __shfl_xor(s[r], 1);
        s[r] += __shfl_xor(s[r], 2);
    }
    const float us = u_scale[iu];
    const float* scp = sc + (size_t)ii * 16;
    // lane c writes relation r=c; lane c==0 also writes r=4
    out[e * NREL + c] = fmaf((float)s[c], us * scp[c], scp[NREL + c]);
    if (c == 0)
        out[e * NREL + 4] = fmaf((float)s[4], us * scp[4], scp[NREL + 4]);
}

extern "C" void kernel_launch(void* const* d_in, const int* in_sizes, int n_in,
                              void* d_out, int out_size, void* d_ws, size_t ws_size,
                              hipStream_t stream) {
    const float* u_feat    = (const float*)d_in[0];
    const float* i_feat    = (const float*)d_in[1];
    const int*   edge_user = (const int*)d_in[2];
    const int*   edge_item = (const int*)d_in[3];
    const float* W         = (const float*)d_in[4];
    const float* b         = (const float*)d_in[5];
    float* out = (float*)d_out;

    const int nUsers = in_sizes[0] / D;
    const int nItems = in_sizes[1] / D;
    const int nE = in_sizes[2];

    // workspace: qrecs (320B/item) | sc (64B/item) | u_q int8 | u_scale fp32
    char* qrecs = (char*)d_ws;
    size_t off = ((size_t)nItems * Q_BYTES + 255) & ~(size_t)255;
    float* sc = (float*)((char*)d_ws + off);
    off += ((size_t)nItems * 16 * sizeof(float) + 255) & ~(size_t)255;
    uint32_t* u_q = (uint32_t*)((char*)d_ws + off);
    off += ((size_t)nUsers * D + 255) & ~(size_t)255;
    float* u_scale = (float*)((char*)d_ws + off);

    {
        const int threads = nUsers * 16;
        u_quant_kernel<<<(threads + 255) / 256, 256, 0, stream>>>(u_feat, u_q, u_scale, nUsers);
    }
    {
        const int nGroups = (nItems + 15) / 16;
        const int waves = NREL * nGroups;
        const int blocks = (waves + 3) / 4;
        item_transform_kernel<<<blocks, 256, 0, stream>>>(i_feat, W, b, qrecs, sc, nItems);
    }
    {
        const long waves = ((long)nE + 15) / 16;
        const long blocks = (waves + 3) / 4;
        edge_kernel<<<(int)blocks, 256, 0, stream>>>(u_q, u_scale, edge_user, edge_item,
                                                     qrecs, sc, out, nE);
    }
}

// Round 7
// 284.133 us; speedup vs baseline: 1.4928x; 1.4479x over previous
//
#include <hip/hip_runtime.h>
#include <stdint.h>

#define NREL 5
#define D 64
#define Q_BYTES 320     // int8 q[5][64] permuted, 5 cache lines
#define NT 21           // 20 value n-tiles + 1 bias tile
// sc[item][16] floats (64B): [0..4]=y scale, [5..9]=c bias-dot, rest pad

typedef __attribute__((ext_vector_type(8))) short short8;
typedef __attribute__((ext_vector_type(4))) float f32x4;

// round-to-nearest-even fp32 -> bf16 bits
static __device__ __forceinline__ short f2bf(float f) {
    uint32_t u = __float_as_uint(f);
    u += 0x7FFFu + ((u >> 16) & 1u);
    return (short)(u >> 16);
}

#if defined(__has_builtin)
#if __has_builtin(__builtin_amdgcn_sdot4)
#define HAVE_SDOT4 1
#endif
#endif
#ifdef HAVE_SDOT4
static __device__ __forceinline__ int SDOT4(uint32_t a, uint32_t b, int c) {
    return __builtin_amdgcn_sdot4((int)a, (int)b, c, false);
}
#else
static __device__ __forceinline__ int SDOT4(uint32_t a, uint32_t b, int c) {
    c += ((int)(a << 24) >> 24) * ((int)(b << 24) >> 24);
    c += ((int)(a << 16) >> 24) * ((int)(b << 16) >> 24);
    c += ((int)(a << 8) >> 24) * ((int)(b << 8) >> 24);
    c += ((int)a >> 24) * ((int)b >> 24);
    return c;
}
#endif

// Kernel A: pack W (+bias as tile 20) into B-fragment-linear bf16 buffer.
// Wf[(nt*2+h)*64 + lane] is a 16B fragment: element j = B[d = h*32+(lane>>4)*8+j]
// [n = nt*16+(lane&15)], where B[d][n] = W[n/64][d][n%64] for n<320, b[n-320][d] else.
__global__ __launch_bounds__(256) void w_prep_kernel(
    const float* __restrict__ W, const float* __restrict__ b, short* __restrict__ Wf)
{
    const int tid = blockIdx.x * 256 + threadIdx.x;
    if (tid >= NT * 2 * 64) return;
    const int lane = tid & 63;
    const int h = (tid >> 6) & 1;
    const int nt = tid >> 7;
    const int ln = lane & 15, quad = lane >> 4;
    const int n = nt * 16 + ln;
    uint32_t w[4];
#pragma unroll
    for (int p = 0; p < 4; ++p) {
        uint32_t lo, hi;
#pragma unroll
        for (int s = 0; s < 2; ++s) {
            const int j = p * 2 + s;
            const int d = h * 32 + quad * 8 + j;
            float v;
            if (nt < 20) v = W[(n >> 6) * (D * D) + d * D + (n & 63)];
            else         v = (ln < NREL) ? b[ln * D + d] : 0.f;
            if (s == 0) lo = (uint16_t)f2bf(v); else hi = (uint16_t)f2bf(v);
        }
        w[p] = lo | (hi << 16);
    }
    *(uint4*)(Wf + (size_t)tid * 8) = make_uint4(w[0], w[1], w[2], w[3]);
}

// Kernel 0: quantize u rows to int8, PERMUTED col order matching the item
// epilogue: byte p = ln*4+tt of the 64B row holds col k = tt*16+ln.
__global__ __launch_bounds__(256) void u_quant_kernel(
    const float* __restrict__ uf,
    uint32_t* __restrict__ uq,
    float* __restrict__ uscale,
    int nRows)
{
    const int gid = blockIdx.x * 256 + threadIdx.x;
    const int row = gid >> 4;
    const int t = gid & 15;
    if (row >= nRows) return;
    const float* rp = uf + (size_t)row * D;
    const float v0 = rp[t], v1 = rp[16 + t], v2 = rp[32 + t], v3 = rp[48 + t];
    float m = fmaxf(fmaxf(fabsf(v0), fabsf(v1)), fmaxf(fabsf(v2), fabsf(v3)));
    m = fmaxf(m, __shfl_xor(m, 1));
    m = fmaxf(m, __shfl_xor(m, 2));
    m = fmaxf(m, __shfl_xor(m, 4));
    m = fmaxf(m, __shfl_xor(m, 8));
    m = fmaxf(m, 1e-20f);
    const float qs = 127.0f / m;
    const int q0 = (int)rintf(v0 * qs);
    const int q1 = (int)rintf(v1 * qs);
    const int q2 = (int)rintf(v2 * qs);
    const int q3 = (int)rintf(v3 * qs);
    uq[(size_t)row * 16 + t] = ((uint32_t)(uint8_t)(int8_t)q0)
                             | ((uint32_t)(uint8_t)(int8_t)q1 << 8)
                             | ((uint32_t)(uint8_t)(int8_t)q2 << 16)
                             | ((uint32_t)(uint8_t)(int8_t)q3 << 24);
    if (t == 0) uscale[row] = m * (1.0f / 127.0f);
}

// Kernel 1: item transform via MFMA. Block = 4 waves = 64 items; wave = 16 items.
// Y[16 x 336] = i_tile[16 x 64] @ B[64 x 336] as 21 16x16 tiles, K split 2x32.
// C/D layout: col = lane&15, row = (lane>>4)*4 + reg.
__global__ __launch_bounds__(256) void item_transform_kernel(
    const float* __restrict__ i_feat,
    const short* __restrict__ Wf,
    char* __restrict__ qrecs,
    float* __restrict__ sc,
    int nItems)
{
    const int lane = threadIdx.x & 63;
    const int wv = threadIdx.x >> 6;
    const int m0 = blockIdx.x * 64 + wv * 16;
    const int ln = lane & 15, quad = lane >> 4;

    // A fragments: A[m=ln][k = quad*8 + j], k-halves h=0,1
    int rowA = m0 + ln;
    if (rowA >= nItems) rowA = nItems - 1;
    const float* ap = i_feat + (size_t)rowA * D + quad * 8;
    short8 af[2];
#pragma unroll
    for (int h = 0; h < 2; ++h) {
        const float4 x = *(const float4*)(ap + h * 32);
        const float4 y = *(const float4*)(ap + h * 32 + 4);
        short8 a;
        a[0] = f2bf(x.x); a[1] = f2bf(x.y); a[2] = f2bf(x.z); a[3] = f2bf(x.w);
        a[4] = f2bf(y.x); a[5] = f2bf(y.y); a[6] = f2bf(y.z); a[7] = f2bf(y.w);
        af[h] = a;
    }

    f32x4 acc[NT];
#pragma unroll
    for (int nt = 0; nt < NT; ++nt) acc[nt] = (f32x4){0.f, 0.f, 0.f, 0.f};

#pragma unroll
    for (int nt = 0; nt < NT; ++nt) {
        const short8 b0 = *(const short8*)(Wf + ((size_t)(nt * 2 + 0) * 64 + lane) * 8);
        acc[nt] = __builtin_amdgcn_mfma_f32_16x16x32_bf16(af[0], b0, acc[nt], 0, 0, 0);
        const short8 b1 = *(const short8*)(Wf + ((size_t)(nt * 2 + 1) * 64 + lane) * 8);
        acc[nt] = __builtin_amdgcn_mfma_f32_16x16x32_bf16(af[1], b1, acc[nt], 0, 0, 0);
    }

    // epilogue: rows item = m0 + quad*4 + g. Per (r,g): absmax over 4 tiles x
    // quad lanes -> int8, pack 4 bytes (permuted: byte tt <-> col tt*16+ln).
#pragma unroll
    for (int g = 0; g < 4; ++g) {
        const int item = m0 + quad * 4 + g;
        const bool ok = (item < nItems);
        char* rec = qrecs + (size_t)item * Q_BYTES;
#pragma unroll
        for (int r = 0; r < NREL; ++r) {
            const float v0 = acc[4 * r + 0][g];
            const float v1 = acc[4 * r + 1][g];
            const float v2 = acc[4 * r + 2][g];
            const float v3 = acc[4 * r + 3][g];
            float m = fmaxf(fmaxf(fabsf(v0), fabsf(v1)), fmaxf(fabsf(v2), fabsf(v3)));
            m = fmaxf(m, __shfl_xor(m, 1));
            m = fmaxf(m, __shfl_xor(m, 2));
            m = fmaxf(m, __shfl_xor(m, 4));
            m = fmaxf(m, __shfl_xor(m, 8));
            m = fmaxf(m, 1e-20f);
            const float qs = 127.0f / m;
            const uint32_t pw = ((uint32_t)(uint8_t)(int8_t)(int)rintf(v0 * qs))
                              | ((uint32_t)(uint8_t)(int8_t)(int)rintf(v1 * qs) << 8)
                              | ((uint32_t)(uint8_t)(int8_t)(int)rintf(v2 * qs) << 16)
                              | ((uint32_t)(uint8_t)(int8_t)(int)rintf(v3 * qs) << 24);
            if (ok) {
                *(uint32_t*)(rec + r * D + ln * 4) = pw;
                if (ln == 0) sc[(size_t)item * 16 + r] = m * (1.0f / 127.0f);
            }
        }
        // bias tile: c[item][r] at col ln==r
        if (ok && ln < NREL) sc[(size_t)item * 16 + NREL + ln] = acc[20][g];
    }
}

// Kernel 2: per-edge gather + int8 dot via sdot4. 4 lanes per edge
// (16 edges/wave). Lane c owns bytes c*16..c*16+15 of each (permuted) row.
__global__ __launch_bounds__(256) void edge_kernel(
    const uint32_t* __restrict__ u_q,
    const float* __restrict__ u_scale,
    const int* __restrict__ edge_user,
    const int* __restrict__ edge_item,
    const char* __restrict__ qrecs,
    const float* __restrict__ sc,
    float* __restrict__ out,
    int nE)
{
    const int lane = threadIdx.x & 63;
    const int wave = (blockIdx.x * 256 + threadIdx.x) >> 6;
    const int es = lane >> 2;    // edge slot 0..15
    const int c = lane & 3;      // 16B chunk

    const long e = (long)wave * 16 + es;
    if (e >= nE) return;

    const int iu = edge_user[e];
    const int ii = edge_item[e];
    const uint4 uv = *(const uint4*)(u_q + (size_t)iu * 16 + c * 4);
    const char* rec = qrecs + (size_t)ii * Q_BYTES;

    int s[NREL];
#pragma unroll
    for (int r = 0; r < NREL; ++r) {
        const uint4 yv = *(const uint4*)(rec + r * D + c * 16);
        int t = SDOT4(uv.x, yv.x, 0);
        t = SDOT4(uv.y, yv.y, t);
        t = SDOT4(uv.z, yv.z, t);
        s[r] = SDOT4(uv.w, yv.w, t);
    }
#pragma unroll
    for (int r = 0; r < NREL; ++r) {
        s[r] += __shfl_xor(s[r], 1);
        s[r] += __shfl_xor(s[r], 2);
    }
    const float us = u_scale[iu];
    const float* scp = sc + (size_t)ii * 16;
    out[e * NREL + c] = fmaf((float)s[c], us * scp[c], scp[NREL + c]);
    if (c == 0)
        out[e * NREL + 4] = fmaf((float)s[4], us * scp[4], scp[NREL + 4]);
}

extern "C" void kernel_launch(void* const* d_in, const int* in_sizes, int n_in,
                              void* d_out, int out_size, void* d_ws, size_t ws_size,
                              hipStream_t stream) {
    const float* u_feat    = (const float*)d_in[0];
    const float* i_feat    = (const float*)d_in[1];
    const int*   edge_user = (const int*)d_in[2];
    const int*   edge_item = (const int*)d_in[3];
    const float* W         = (const float*)d_in[4];
    const float* b         = (const float*)d_in[5];
    float* out = (float*)d_out;

    const int nUsers = in_sizes[0] / D;
    const int nItems = in_sizes[1] / D;
    const int nE = in_sizes[2];

    // workspace: qrecs | sc | u_q | u_scale | Wf
    char* qrecs = (char*)d_ws;
    size_t off = ((size_t)nItems * Q_BYTES + 255) & ~(size_t)255;
    float* sc = (float*)((char*)d_ws + off);
    off += ((size_t)nItems * 16 * sizeof(float) + 255) & ~(size_t)255;
    uint32_t* u_q = (uint32_t*)((char*)d_ws + off);
    off += ((size_t)nUsers * D + 255) & ~(size_t)255;
    float* u_scale = (float*)((char*)d_ws + off);
    off += ((size_t)nUsers * sizeof(float) + 255) & ~(size_t)255;
    short* Wf = (short*)((char*)d_ws + off);

    {
        const int threads = NT * 2 * 64;
        w_prep_kernel<<<(threads + 255) / 256, 256, 0, stream>>>(W, b, Wf);
    }
    {
        const int threads = nUsers * 16;
        u_quant_kernel<<<(threads + 255) / 256, 256, 0, stream>>>(u_feat, u_q, u_scale, nUsers);
    }
    {
        const int blocks = (nItems + 63) / 64;
        item_transform_kernel<<<blocks, 256, 0, stream>>>(i_feat, Wf, qrecs, sc, nItems);
    }
    {
        const long waves = ((long)nE + 15) / 16;
        const long blocks = (waves + 3) / 4;
        edge_kernel<<<(int)blocks, 256, 0, stream>>>(u_q, u_scale, edge_user, edge_item,
                                                     qrecs, sc, out, nE);
    }
}

// Round 8
// 276.867 us; speedup vs baseline: 1.5320x; 1.0262x over previous
//
#include <hip/hip_runtime.h>
#include <stdint.h>

#define NREL 5
#define D 64
#define Q_BYTES 320     // int8 q[5][64] permuted, 5 cache lines (320B-aligned stride)
#define NT 21           // 20 value n-tiles + 1 bias tile
#define NB 8            // item buckets (one per XCD)
#define CHUNK 2048      // edges per sort block
// sc[item][16] floats (64B): [0..4]=y scale, [5..9]=c bias-dot, rest pad

typedef __attribute__((ext_vector_type(8))) short short8;
typedef __attribute__((ext_vector_type(4))) float f32x4;

// round-to-nearest-even fp32 -> bf16 bits
static __device__ __forceinline__ short f2bf(float f) {
    uint32_t u = __float_as_uint(f);
    u += 0x7FFFu + ((u >> 16) & 1u);
    return (short)(u >> 16);
}

#if defined(__has_builtin)
#if __has_builtin(__builtin_amdgcn_sdot4)
#define HAVE_SDOT4 1
#endif
#endif
#ifdef HAVE_SDOT4
static __device__ __forceinline__ int SDOT4(uint32_t a, uint32_t b, int c) {
    return __builtin_amdgcn_sdot4((int)a, (int)b, c, false);
}
#else
static __device__ __forceinline__ int SDOT4(uint32_t a, uint32_t b, int c) {
    c += ((int)(a << 24) >> 24) * ((int)(b << 24) >> 24);
    c += ((int)(a << 16) >> 24) * ((int)(b << 16) >> 24);
    c += ((int)(a << 8) >> 24) * ((int)(b << 8) >> 24);
    c += ((int)a >> 24) * ((int)b >> 24);
    return c;
}
#endif

// ---------- Kernel A: pack W (+bias as tile 20) into B-fragment bf16 ----------
__global__ __launch_bounds__(256) void w_prep_kernel(
    const float* __restrict__ W, const float* __restrict__ b, short* __restrict__ Wf)
{
    const int tid = blockIdx.x * 256 + threadIdx.x;
    if (tid >= NT * 2 * 64) return;
    const int lane = tid & 63;
    const int h = (tid >> 6) & 1;
    const int nt = tid >> 7;
    const int ln = lane & 15, quad = lane >> 4;
    const int n = nt * 16 + ln;
    uint32_t w[4];
#pragma unroll
    for (int p = 0; p < 4; ++p) {
        uint32_t lo = 0, hi = 0;
#pragma unroll
        for (int s = 0; s < 2; ++s) {
            const int j = p * 2 + s;
            const int d = h * 32 + quad * 8 + j;
            float v;
            if (nt < 20) v = W[(n >> 6) * (D * D) + d * D + (n & 63)];
            else         v = (ln < NREL) ? b[ln * D + d] : 0.f;
            if (s == 0) lo = (uint16_t)f2bf(v); else hi = (uint16_t)f2bf(v);
        }
        w[p] = lo | (hi << 16);
    }
    *(uint4*)(Wf + (size_t)tid * 8) = make_uint4(w[0], w[1], w[2], w[3]);
}

// ---------- Kernel 0: u rows -> int8 (permuted col order) + per-row scale ----------
__global__ __launch_bounds__(256) void u_quant_kernel(
    const float* __restrict__ uf,
    uint32_t* __restrict__ uq,
    float* __restrict__ uscale,
    int nRows)
{
    const int gid = blockIdx.x * 256 + threadIdx.x;
    const int row = gid >> 4;
    const int t = gid & 15;
    if (row >= nRows) return;
    const float* rp = uf + (size_t)row * D;
    const float v0 = rp[t], v1 = rp[16 + t], v2 = rp[32 + t], v3 = rp[48 + t];
    float m = fmaxf(fmaxf(fabsf(v0), fabsf(v1)), fmaxf(fabsf(v2), fabsf(v3)));
    m = fmaxf(m, __shfl_xor(m, 1));
    m = fmaxf(m, __shfl_xor(m, 2));
    m = fmaxf(m, __shfl_xor(m, 4));
    m = fmaxf(m, __shfl_xor(m, 8));
    m = fmaxf(m, 1e-20f);
    const float qs = 127.0f / m;
    const int q0 = (int)rintf(v0 * qs);
    const int q1 = (int)rintf(v1 * qs);
    const int q2 = (int)rintf(v2 * qs);
    const int q3 = (int)rintf(v3 * qs);
    uq[(size_t)row * 16 + t] = ((uint32_t)(uint8_t)(int8_t)q0)
                             | ((uint32_t)(uint8_t)(int8_t)q1 << 8)
                             | ((uint32_t)(uint8_t)(int8_t)q2 << 16)
                             | ((uint32_t)(uint8_t)(int8_t)q3 << 24);
    if (t == 0) uscale[row] = m * (1.0f / 127.0f);
}

// ---------- Kernel 1: item transform via MFMA (unchanged from R7) ----------
__global__ __launch_bounds__(256) void item_transform_kernel(
    const float* __restrict__ i_feat,
    const short* __restrict__ Wf,
    char* __restrict__ qrecs,
    float* __restrict__ sc,
    int nItems)
{
    const int lane = threadIdx.x & 63;
    const int wv = threadIdx.x >> 6;
    const int m0 = blockIdx.x * 64 + wv * 16;
    const int ln = lane & 15, quad = lane >> 4;

    int rowA = m0 + ln;
    if (rowA >= nItems) rowA = nItems - 1;
    const float* ap = i_feat + (size_t)rowA * D + quad * 8;
    short8 af[2];
#pragma unroll
    for (int h = 0; h < 2; ++h) {
        const float4 x = *(const float4*)(ap + h * 32);
        const float4 y = *(const float4*)(ap + h * 32 + 4);
        short8 a;
        a[0] = f2bf(x.x); a[1] = f2bf(x.y); a[2] = f2bf(x.z); a[3] = f2bf(x.w);
        a[4] = f2bf(y.x); a[5] = f2bf(y.y); a[6] = f2bf(y.z); a[7] = f2bf(y.w);
        af[h] = a;
    }

    f32x4 acc[NT];
#pragma unroll
    for (int nt = 0; nt < NT; ++nt) acc[nt] = (f32x4){0.f, 0.f, 0.f, 0.f};

#pragma unroll
    for (int nt = 0; nt < NT; ++nt) {
        const short8 b0 = *(const short8*)(Wf + ((size_t)(nt * 2 + 0) * 64 + lane) * 8);
        acc[nt] = __builtin_amdgcn_mfma_f32_16x16x32_bf16(af[0], b0, acc[nt], 0, 0, 0);
        const short8 b1 = *(const short8*)(Wf + ((size_t)(nt * 2 + 1) * 64 + lane) * 8);
        acc[nt] = __builtin_amdgcn_mfma_f32_16x16x32_bf16(af[1], b1, acc[nt], 0, 0, 0);
    }

#pragma unroll
    for (int g = 0; g < 4; ++g) {
        const int item = m0 + quad * 4 + g;
        const bool ok = (item < nItems);
        char* rec = qrecs + (size_t)item * Q_BYTES;
#pragma unroll
        for (int r = 0; r < NREL; ++r) {
            const float v0 = acc[4 * r + 0][g];
            const float v1 = acc[4 * r + 1][g];
            const float v2 = acc[4 * r + 2][g];
            const float v3 = acc[4 * r + 3][g];
            float m = fmaxf(fmaxf(fabsf(v0), fabsf(v1)), fmaxf(fabsf(v2), fabsf(v3)));
            m = fmaxf(m, __shfl_xor(m, 1));
            m = fmaxf(m, __shfl_xor(m, 2));
            m = fmaxf(m, __shfl_xor(m, 4));
            m = fmaxf(m, __shfl_xor(m, 8));
            m = fmaxf(m, 1e-20f);
            const float qs = 127.0f / m;
            const uint32_t pw = ((uint32_t)(uint8_t)(int8_t)(int)rintf(v0 * qs))
                              | ((uint32_t)(uint8_t)(int8_t)(int)rintf(v1 * qs) << 8)
                              | ((uint32_t)(uint8_t)(int8_t)(int)rintf(v2 * qs) << 16)
                              | ((uint32_t)(uint8_t)(int8_t)(int)rintf(v3 * qs) << 24);
            if (ok) {
                *(uint32_t*)(rec + r * D + ln * 4) = pw;
                if (ln == 0) sc[(size_t)item * 16 + r] = m * (1.0f / 127.0f);
            }
        }
        if (ok && ln < NREL) sc[(size_t)item * 16 + NREL + ln] = acc[20][g];
    }
}

// ---------- Kernel S1: per-block bucket histogram ----------
__global__ __launch_bounds__(256) void hist_kernel(
    const int* __restrict__ edge_item, int nE, int bucketDiv,
    int* __restrict__ blkHist)
{
    __shared__ int cnt[NB];
    if (threadIdx.x < NB) cnt[threadIdx.x] = 0;
    __syncthreads();
    const long start = (long)blockIdx.x * CHUNK;
#pragma unroll
    for (int k = 0; k < CHUNK / 256; ++k) {
        const long e = start + k * 256 + threadIdx.x;
        if (e < nE) atomicAdd(&cnt[edge_item[e] / bucketDiv], 1);
    }
    __syncthreads();
    if (threadIdx.x < NB) blkHist[blockIdx.x * NB + threadIdx.x] = cnt[threadIdx.x];
}

// ---------- Kernel S2: scan blkHist columns -> per-block bases; bucketBase ----------
// 1 block x 512 threads; wave w scans bucket-column w.
__global__ __launch_bounds__(512) void scan_kernel(
    int* __restrict__ blkHist, int nBlocks, int* __restrict__ bucketBase)
{
    __shared__ int tot[NB];
    __shared__ int base[NB + 1];
    const int lane = threadIdx.x & 63;
    const int b = threadIdx.x >> 6;   // 0..7
    int carry = 0;
    for (int c0 = 0; c0 < nBlocks; c0 += 64) {
        const int idx = c0 + lane;
        int v = (idx < nBlocks) ? blkHist[idx * NB + b] : 0;
        int s = v;
#pragma unroll
        for (int d = 1; d < 64; d <<= 1) {
            int t = __shfl_up(s, d);
            if (lane >= d) s += t;
        }
        if (idx < nBlocks) blkHist[idx * NB + b] = carry + s - v;  // exclusive, bucket-rel
        carry += __shfl(s, 63);
    }
    if (lane == 0) tot[b] = carry;
    __syncthreads();
    if (threadIdx.x == 0) {
        int s = 0;
#pragma unroll
        for (int i = 0; i < NB; ++i) { base[i] = s; s += tot[i]; }
        base[NB] = s;
#pragma unroll
        for (int i = 0; i <= NB; ++i) bucketBase[i] = base[i];
    }
    __syncthreads();
    const int add = base[b];
    for (int c0 = 0; c0 < nBlocks; c0 += 64) {
        const int idx = c0 + lane;
        if (idx < nBlocks) blkHist[idx * NB + b] += add;
    }
}

// ---------- Kernel S3: scatter edges into bucket-sorted array ----------
// packed u64: user(17b) | item(16b)<<17 | e(31b)<<33
__global__ __launch_bounds__(256) void scatter_kernel(
    const int* __restrict__ edge_user, const int* __restrict__ edge_item,
    int nE, int bucketDiv, const int* __restrict__ blkHist,
    unsigned long long* __restrict__ sorted)
{
    __shared__ int cnt[NB];
    __shared__ int base[NB];
    if (threadIdx.x < NB) {
        cnt[threadIdx.x] = 0;
        base[threadIdx.x] = blkHist[blockIdx.x * NB + threadIdx.x];
    }
    __syncthreads();
    const long start = (long)blockIdx.x * CHUNK;
#pragma unroll
    for (int k = 0; k < CHUNK / 256; ++k) {
        const long e = start + k * 256 + threadIdx.x;
        if (e < nE) {
            const int iu = edge_user[e];
            const int ii = edge_item[e];
            const int b = ii / bucketDiv;
            const int rank = atomicAdd(&cnt[b], 1);
            const unsigned long long pk = (unsigned long long)(uint32_t)iu
                                        | ((unsigned long long)(uint32_t)ii << 17)
                                        | ((unsigned long long)e << 33);
            sorted[base[b] + rank] = pk;
        }
    }
}

// ---------- Kernel 2: bucket-ordered edge gather + int8 dot ----------
// bucket = blockIdx & 7 (XCD round-robin); segments stream each bucket in order.
__global__ __launch_bounds__(256) void edge_kernel(
    const uint32_t* __restrict__ u_q,
    const float* __restrict__ u_scale,
    const unsigned long long* __restrict__ sorted,
    const int* __restrict__ bucketBase,
    const char* __restrict__ qrecs,
    const float* __restrict__ sc,
    float* __restrict__ out)
{
    const int b = blockIdx.x & 7;
    const int seg = blockIdx.x >> 3;
    const int nSeg = gridDim.x >> 3;
    const int s0 = bucketBase[b], s1 = bucketBase[b + 1];
    const int cnt = s1 - s0;
    const int per = (cnt + nSeg - 1) / nSeg;
    const int p0 = s0 + seg * per;
    const int p1 = min(p0 + per, s1);

    const int lane = threadIdx.x & 63;
    const int wv = threadIdx.x >> 6;
    const int es = lane >> 2;   // edge slot 0..15
    const int c = lane & 3;     // 16B chunk

    for (int q0 = p0 + wv * 16; q0 < p1; q0 += 64) {
        const int pos = q0 + es;
        if (pos < p1) {
            const unsigned long long pk = sorted[pos];
            const int iu = (int)(pk & 0x1FFFF);
            const int ii = (int)((pk >> 17) & 0xFFFF);
            const long e = (long)(pk >> 33);

            const uint4 uv = *(const uint4*)(u_q + (size_t)iu * 16 + c * 4);
            const char* rec = qrecs + (size_t)ii * Q_BYTES;

            int s[NREL];
#pragma unroll
            for (int r = 0; r < NREL; ++r) {
                const uint4 yv = *(const uint4*)(rec + r * D + c * 16);
                int t = SDOT4(uv.x, yv.x, 0);
                t = SDOT4(uv.y, yv.y, t);
                t = SDOT4(uv.z, yv.z, t);
                s[r] = SDOT4(uv.w, yv.w, t);
            }
#pragma unroll
            for (int r = 0; r < NREL; ++r) {
                s[r] += __shfl_xor(s[r], 1);
                s[r] += __shfl_xor(s[r], 2);
            }
            const float us = u_scale[iu];
            const float* scp = sc + (size_t)ii * 16;
            out[e * NREL + c] = fmaf((float)s[c], us * scp[c], scp[NREL + c]);
            if (c == 0)
                out[e * NREL + 4] = fmaf((float)s[4], us * scp[4], scp[NREL + 4]);
        }
    }
}

extern "C" void kernel_launch(void* const* d_in, const int* in_sizes, int n_in,
                              void* d_out, int out_size, void* d_ws, size_t ws_size,
                              hipStream_t stream) {
    const float* u_feat    = (const float*)d_in[0];
    const float* i_feat    = (const float*)d_in[1];
    const int*   edge_user = (const int*)d_in[2];
    const int*   edge_item = (const int*)d_in[3];
    const float* W         = (const float*)d_in[4];
    const float* b         = (const float*)d_in[5];
    float* out = (float*)d_out;

    const int nUsers = in_sizes[0] / D;
    const int nItems = in_sizes[1] / D;
    const int nE = in_sizes[2];
    const int bucketDiv = (nItems + NB - 1) / NB;
    const int nBlocksSort = (nE + CHUNK - 1) / CHUNK;

    // workspace: qrecs | sc | u_q | u_scale | Wf | blkHist | bucketBase | sorted
    size_t off = 0;
    char* qrecs = (char*)d_ws;
    off += ((size_t)nItems * Q_BYTES + 255) & ~(size_t)255;
    float* sc = (float*)((char*)d_ws + off);
    off += ((size_t)nItems * 16 * sizeof(float) + 255) & ~(size_t)255;
    uint32_t* u_q = (uint32_t*)((char*)d_ws + off);
    off += ((size_t)nUsers * D + 255) & ~(size_t)255;
    float* u_scale = (float*)((char*)d_ws + off);
    off += ((size_t)nUsers * sizeof(float) + 255) & ~(size_t)255;
    short* Wf = (short*)((char*)d_ws + off);
    off += ((size_t)NT * 2 * 64 * 8 * sizeof(short) + 255) & ~(size_t)255;
    int* blkHist = (int*)((char*)d_ws + off);
    off += ((size_t)nBlocksSort * NB * sizeof(int) + 255) & ~(size_t)255;
    int* bucketBase = (int*)((char*)d_ws + off);
    off += 256;
    unsigned long long* sorted = (unsigned long long*)((char*)d_ws + off);

    {
        const int threads = NT * 2 * 64;
        w_prep_kernel<<<(threads + 255) / 256, 256, 0, stream>>>(W, b, Wf);
    }
    {
        const int threads = nUsers * 16;
        u_quant_kernel<<<(threads + 255) / 256, 256, 0, stream>>>(u_feat, u_q, u_scale, nUsers);
    }
    {
        const int blocks = (nItems + 63) / 64;
        item_transform_kernel<<<blocks, 256, 0, stream>>>(i_feat, Wf, qrecs, sc, nItems);
    }
    hist_kernel<<<nBlocksSort, 256, 0, stream>>>(edge_item, nE, bucketDiv, blkHist);
    scan_kernel<<<1, 512, 0, stream>>>(blkHist, nBlocksSort, bucketBase);
    scatter_kernel<<<nBlocksSort, 256, 0, stream>>>(edge_user, edge_item, nE, bucketDiv,
                                                    blkHist, sorted);
    edge_kernel<<<1280, 256, 0, stream>>>(u_q, u_scale, sorted, bucketBase,
                                          qrecs, sc, out);
}